// Round 14
// baseline (527.974 us; speedup 1.0000x reference)
//
#include <hip/hip_runtime.h>

#define N_ENT 100000
#define HDIM  200
#define NEDGE 1000000
#define BDIM  512
#define PITCH 224            // bf16 row pitch (elems); 448B, 64B-aligned
#define PITCH8 256           // fp8 row pitch (bytes); 64B-aligned
#define NSEG  28             // PITCH/8
#define NF    13             // 13 x 16 = 208 output cols
#define OUTS_W 212           // LDS stride: 128*212*2=54272B -> 3 blocks/CU, conflict-free
#define SCAN_TILE 1024
#define SCAN_NB   ((N_ENT + SCAN_TILE - 1)/SCAN_TILE)   // 98
#define BN_NB 32
#define REL8_WORDS (460*PITCH8/4)   // 29440 4-byte words
#define BP_ELEMS   (14*NF*64*8)     // 93184

typedef short  short8v __attribute__((ext_vector_type(8)));
typedef float  float4v __attribute__((ext_vector_type(4)));
typedef float  float2v __attribute__((ext_vector_type(2)));

__device__ __forceinline__ float rrelu_f(float v){
    const float slope = (1.0f/8.0f + 1.0f/3.0f)*0.5f;
    return v >= 0.f ? v : v*slope;
}
__device__ __forceinline__ unsigned short f2bf(float f){
    unsigned int x = __float_as_uint(f);
    unsigned int r = (x + 0x7fffu + ((x >> 16) & 1u)) >> 16;
    return (unsigned short)r;
}
__device__ __forceinline__ float bf2f(unsigned short u){
    return __uint_as_float(((unsigned int)u) << 16);
}
__device__ __forceinline__ unsigned int pack_fp8x4(float a, float b, float c, float d){
    unsigned int w = 0;
    w = __builtin_amdgcn_cvt_pk_fp8_f32(a, b, w, false);
    w = __builtin_amdgcn_cvt_pk_fp8_f32(c, d, w, true);
    return w;
}

// ---- fused init: deg=0 | rel8 | Bp1 | Bp2 | Xbuf1/X8_1=ent | gate -------
__device__ __forceinline__ void pack_b(int b, const float* __restrict__ Wn,
        const float* __restrict__ Wl, unsigned short* __restrict__ Bp){
    int i = b*1024 + threadIdx.x*4;
    #pragma unroll
    for (int k=0;k<4;k++){
        int idx = i+k;
        if (idx < BP_ELEMS){
            int j = idx & 7, l = (idx >> 3) & 63, rest = idx >> 9;
            int f = rest % NF, ks = rest / NF;
            int kk = ks*32 + ((l >> 4) << 3) + j;
            int c  = f*16 + (l & 15);
            float v = 0.f;
            if (c < HDIM){
                if (kk < 200)                   v = Wn[(size_t)kk*HDIM + c];
                else if (kk >= 224 && kk < 424) v = Wl[(size_t)(kk-224)*HDIM + c];
            }
            Bp[idx] = f2bf(v);
        }
    }
}

__global__ __launch_bounds__(256) void init_k(const float* __restrict__ ent,
        const float* __restrict__ rel,
        const float* __restrict__ Wn1, const float* __restrict__ Wl1,
        const float* __restrict__ Wn2, const float* __restrict__ Wl2,
        const float* __restrict__ gtheta, const float* __restrict__ gw,
        const float* __restrict__ gb,
        int* __restrict__ deg, unsigned int* __restrict__ rel8,
        unsigned short* __restrict__ Bp1, unsigned short* __restrict__ Bp2,
        unsigned short* __restrict__ Xbuf1, unsigned char* __restrict__ X8_1,
        float* __restrict__ gate){
    int b = blockIdx.x;
    if (b < 98){
        int i = b*1024 + threadIdx.x*4;
        if (i+3 < N_ENT) *(int4*)(deg+i) = make_int4(0,0,0,0);
        else { for (int k=0;k<4;k++) if (i+k < N_ENT) deg[i+k]=0; }
        return;
    }
    b -= 98;
    if (b < 29){
        int i = b*1024 + threadIdx.x*4;
        #pragma unroll
        for (int k=0;k<4;k++){
            int idx = i+k;
            if (idx < REL8_WORDS){
                int r = idx >> 6;              // 64 words per 256B row
                int c = (idx & 63) * 4;        // elem offset
                float v0=0.f,v1=0.f,v2=0.f,v3=0.f;
                if (c < HDIM){
                    const float* rp = rel + (size_t)r*HDIM + c;
                    v0 = rp[0];
                    if (c+1 < HDIM) v1 = rp[1];
                    if (c+2 < HDIM) v2 = rp[2];
                    if (c+3 < HDIM) v3 = rp[3];
                }
                rel8[idx] = pack_fp8x4(v0,v1,v2,v3);
            }
        }
        return;
    }
    b -= 29;
    if (b < 91){ pack_b(b, Wn1, Wl1, Bp1); return; }
    b -= 91;
    if (b < 91){ pack_b(b, Wn2, Wl2, Bp2); return; }
    b -= 91;
    int w = threadIdx.x >> 6, l = threadIdx.x & 63;
    if (b < N_ENT/4){
        // Xbuf1 (bf16) + X8_1 (fp8), 4 rows/block
        if (l >= 56) return;
        int n = b*4 + w;
        int el = 4*l;
        ushort4 o;
        float4 v = make_float4(0.f,0.f,0.f,0.f);
        if (el < HDIM) v = *(const float4*)(ent + (size_t)n*HDIM + el);
        o.x=f2bf(v.x); o.y=f2bf(v.y); o.z=f2bf(v.z); o.w=f2bf(v.w);
        *(ushort4*)(Xbuf1 + (size_t)n*PITCH + el) = o;
        *(unsigned int*)(X8_1 + (size_t)n*PITCH8 + el) = pack_fp8x4(v.x,v.y,v.z,v.w);
        return;
    }
    b -= N_ENT/4;
    {   // gate: 4 nodes/block, one wave each
        int n = b*4 + w;
        const float* t = gtheta + (size_t)n*HDIM;
        float s = t[l]*gw[l] + t[64+l]*gw[64+l] + t[128+l]*gw[128+l];
        if (l<8) s += t[192+l]*gw[192+l];
        #pragma unroll
        for (int off=32; off>=1; off>>=1) s += __shfl_xor(s, off);
        if (l==0) gate[n] = 1.f/(1.f + expf(-(s + gb[0])));
    }
}

// ---- CSR build ----------------------------------------------------------
__global__ void hist_k(const int* __restrict__ dst, int* __restrict__ deg){
    int e = blockIdx.x*blockDim.x + threadIdx.x;
    if (e < NEDGE) atomicAdd(&deg[dst[e]], 1);
}

__global__ __launch_bounds__(256) void scan_part_k(const int* __restrict__ deg, int* __restrict__ partial){
    int t = threadIdx.x;
    int base = blockIdx.x*SCAN_TILE + t*4;
    int s = 0;
    if (base + 3 < N_ENT){
        int4 v = *(const int4*)(deg + base);
        s = v.x + v.y + v.z + v.w;
    } else {
        for (int i=0;i<4;i++) if (base+i < N_ENT) s += deg[base+i];
    }
    #pragma unroll
    for (int off=32; off>=1; off>>=1) s += __shfl_xor(s, off);
    __shared__ int ws[4];
    if ((t&63)==0) ws[t>>6] = s;
    __syncthreads();
    if (t==0) partial[blockIdx.x] = ws[0]+ws[1]+ws[2]+ws[3];
}

__global__ void scan_mid_k(int* __restrict__ partial){
    __shared__ int sh[128];
    int t = threadIdx.x;
    int v = (t < SCAN_NB) ? partial[t] : 0;
    sh[t] = v;
    __syncthreads();
    for (int off=1; off<128; off<<=1){
        int u = (t>=off) ? sh[t-off] : 0;
        __syncthreads();
        sh[t] += u;
        __syncthreads();
    }
    if (t < SCAN_NB) partial[t] = sh[t] - v;   // exclusive
}

__global__ __launch_bounds__(256) void scan_fin_k(const int* __restrict__ deg, const int* __restrict__ partial,
        int* __restrict__ row_off, int* __restrict__ fill_pos){
    int t = threadIdx.x;
    int lane = t & 63;
    int base = blockIdx.x*SCAN_TILE + t*4;
    int v0=0,v1=0,v2=0,v3=0;
    if (base+3 < N_ENT){
        int4 v = *(const int4*)(deg + base);
        v0=v.x; v1=v.y; v2=v.z; v3=v.w;
    } else {
        if (base   < N_ENT) v0 = deg[base];
        if (base+1 < N_ENT) v1 = deg[base+1];
        if (base+2 < N_ENT) v2 = deg[base+2];
        if (base+3 < N_ENT) v3 = deg[base+3];
    }
    int s = v0+v1+v2+v3;
    int inc = s;
    #pragma unroll
    for (int off=1; off<64; off<<=1){
        int u = __shfl_up(inc, off);
        if (lane >= off) inc += u;
    }
    __shared__ int wsum[4];
    if (lane==63) wsum[t>>6] = inc;
    __syncthreads();
    int w = t>>6;
    int woff = 0;
    for (int i=0;i<w;i++) woff += wsum[i];
    int exc = partial[blockIdx.x] + woff + inc - s;
    int r0 = exc, r1 = exc+v0, r2 = exc+v0+v1, r3 = exc+v0+v1+v2;
    if (base+3 < N_ENT){
        *(int4*)(row_off+base)  = make_int4(r0,r1,r2,r3);
        *(int4*)(fill_pos+base) = make_int4(r0,r1,r2,r3);
    } else {
        if (base   < N_ENT){ row_off[base]  =r0; fill_pos[base]  =r0; }
        if (base+1 < N_ENT){ row_off[base+1]=r1; fill_pos[base+1]=r1; }
        if (base+2 < N_ENT){ row_off[base+2]=r2; fill_pos[base+2]=r2; }
        if (base+3 < N_ENT){ row_off[base+3]=r3; fill_pos[base+3]=r3; }
    }
    if (blockIdx.x==0 && t==0) row_off[N_ENT] = NEDGE;
}

__global__ void fill_k(const int* __restrict__ src, const int* __restrict__ dst, const int* __restrict__ et,
                       int* __restrict__ fill_pos, int2* __restrict__ cs){
    int e = blockIdx.x*blockDim.x + threadIdx.x;
    if (e < NEDGE){
        int p = atomicAdd(&fill_pos[dst[e]], 1);
        cs[p] = make_int2(src[e], et[e]);
    }
}

// ---- spmm layer 1: fp8 X-gather + fp8 rel-gather, write P1 and relavg ---
__global__ __launch_bounds__(256) void spmm1_k(const unsigned char* __restrict__ X8,
        unsigned short* __restrict__ P,
        const unsigned char* __restrict__ rel8,
        const int2* __restrict__ cs,
        const int* __restrict__ row_off,
        unsigned short* __restrict__ relavg){
    int wv = (blockIdx.x*256 + threadIdx.x) >> 6;
    int l = threadIdx.x & 63;
    if (l >= 56) return;
    int beg = row_off[wv], end = row_off[wv+1];
    const int el = 4*l;
    float x0=0.f,x1=0.f,x2=0.f,x3=0.f;
    float r0=0.f,r1=0.f,r2=0.f,r3=0.f;
    int e = beg;
    for (; e+4 <= end; e+=4){
        int2 c0 = cs[e], c1 = cs[e+1], c2 = cs[e+2], c3 = cs[e+3];
        unsigned int ua = *(const unsigned int*)(X8 + (size_t)c0.x*PITCH8 + el);
        unsigned int ub = *(const unsigned int*)(X8 + (size_t)c1.x*PITCH8 + el);
        unsigned int uc = *(const unsigned int*)(X8 + (size_t)c2.x*PITCH8 + el);
        unsigned int ud = *(const unsigned int*)(X8 + (size_t)c3.x*PITCH8 + el);
        unsigned int va = *(const unsigned int*)(rel8 + (size_t)c0.y*PITCH8 + el);
        unsigned int vb = *(const unsigned int*)(rel8 + (size_t)c1.y*PITCH8 + el);
        unsigned int vc = *(const unsigned int*)(rel8 + (size_t)c2.y*PITCH8 + el);
        unsigned int vd = *(const unsigned int*)(rel8 + (size_t)c3.y*PITCH8 + el);
        float2v alo = __builtin_amdgcn_cvt_pk_f32_fp8((int)ua, false);
        float2v ahi = __builtin_amdgcn_cvt_pk_f32_fp8((int)ua, true);
        float2v blo = __builtin_amdgcn_cvt_pk_f32_fp8((int)ub, false);
        float2v bhi = __builtin_amdgcn_cvt_pk_f32_fp8((int)ub, true);
        float2v clo = __builtin_amdgcn_cvt_pk_f32_fp8((int)uc, false);
        float2v chi = __builtin_amdgcn_cvt_pk_f32_fp8((int)uc, true);
        float2v dlo = __builtin_amdgcn_cvt_pk_f32_fp8((int)ud, false);
        float2v dhi = __builtin_amdgcn_cvt_pk_f32_fp8((int)ud, true);
        float2v ralo = __builtin_amdgcn_cvt_pk_f32_fp8((int)va, false);
        float2v rahi = __builtin_amdgcn_cvt_pk_f32_fp8((int)va, true);
        float2v rblo = __builtin_amdgcn_cvt_pk_f32_fp8((int)vb, false);
        float2v rbhi = __builtin_amdgcn_cvt_pk_f32_fp8((int)vb, true);
        float2v rclo = __builtin_amdgcn_cvt_pk_f32_fp8((int)vc, false);
        float2v rchi = __builtin_amdgcn_cvt_pk_f32_fp8((int)vc, true);
        float2v rdlo = __builtin_amdgcn_cvt_pk_f32_fp8((int)vd, false);
        float2v rdhi = __builtin_amdgcn_cvt_pk_f32_fp8((int)vd, true);
        x0 += alo[0]+blo[0]+clo[0]+dlo[0];
        x1 += alo[1]+blo[1]+clo[1]+dlo[1];
        x2 += ahi[0]+bhi[0]+chi[0]+dhi[0];
        x3 += ahi[1]+bhi[1]+chi[1]+dhi[1];
        r0 += ralo[0]+rblo[0]+rclo[0]+rdlo[0];
        r1 += ralo[1]+rblo[1]+rclo[1]+rdlo[1];
        r2 += rahi[0]+rbhi[0]+rchi[0]+rdhi[0];
        r3 += rahi[1]+rbhi[1]+rchi[1]+rdhi[1];
    }
    for (; e<end; e++){
        int2 c0 = cs[e];
        unsigned int ua = *(const unsigned int*)(X8 + (size_t)c0.x*PITCH8 + el);
        unsigned int va = *(const unsigned int*)(rel8 + (size_t)c0.y*PITCH8 + el);
        float2v alo = __builtin_amdgcn_cvt_pk_f32_fp8((int)ua, false);
        float2v ahi = __builtin_amdgcn_cvt_pk_f32_fp8((int)ua, true);
        float2v ralo = __builtin_amdgcn_cvt_pk_f32_fp8((int)va, false);
        float2v rahi = __builtin_amdgcn_cvt_pk_f32_fp8((int)va, true);
        x0 += alo[0]; x1 += alo[1]; x2 += ahi[0]; x3 += ahi[1];
        r0 += ralo[0]; r1 += ralo[1]; r2 += rahi[0]; r3 += rahi[1];
    }
    float id = 1.f / fmaxf((float)(end-beg), 1.f);
    float g0 = r0*id, g1 = r1*id, g2 = r2*id, g3 = r3*id;
    ushort4 rv; rv.x=f2bf(g0); rv.y=f2bf(g1); rv.z=f2bf(g2); rv.w=f2bf(g3);
    *(ushort4*)(relavg + (size_t)wv*PITCH + el) = rv;
    ushort4 o;
    o.x=f2bf(x0*id+g0); o.y=f2bf(x1*id+g1); o.z=f2bf(x2*id+g2); o.w=f2bf(x3*id+g3);
    *(ushort4*)(P + (size_t)wv*PITCH + el) = o;
}

// ---- spmm layer 2: fp8 X-gather + stream relavg, write P2 ---------------
__global__ __launch_bounds__(256) void spmm2_k(const unsigned char* __restrict__ X8,
        unsigned short* __restrict__ P,
        const unsigned short* __restrict__ relavg,
        const int2* __restrict__ cs,
        const int* __restrict__ row_off){
    int wv = (blockIdx.x*256 + threadIdx.x) >> 6;
    int l = threadIdx.x & 63;
    if (l >= 56) return;
    int beg = row_off[wv], end = row_off[wv+1];
    const int el = 4*l;
    ushort4 rv = *(const ushort4*)(relavg + (size_t)wv*PITCH + el);
    float x0=0.f,x1=0.f,x2=0.f,x3=0.f;
    int e = beg;
    for (; e+4 <= end; e+=4){
        int2 c0 = cs[e], c1 = cs[e+1], c2 = cs[e+2], c3 = cs[e+3];
        unsigned int ua = *(const unsigned int*)(X8 + (size_t)c0.x*PITCH8 + el);
        unsigned int ub = *(const unsigned int*)(X8 + (size_t)c1.x*PITCH8 + el);
        unsigned int uc = *(const unsigned int*)(X8 + (size_t)c2.x*PITCH8 + el);
        unsigned int ud = *(const unsigned int*)(X8 + (size_t)c3.x*PITCH8 + el);
        float2v alo = __builtin_amdgcn_cvt_pk_f32_fp8((int)ua, false);
        float2v ahi = __builtin_amdgcn_cvt_pk_f32_fp8((int)ua, true);
        float2v blo = __builtin_amdgcn_cvt_pk_f32_fp8((int)ub, false);
        float2v bhi = __builtin_amdgcn_cvt_pk_f32_fp8((int)ub, true);
        float2v clo = __builtin_amdgcn_cvt_pk_f32_fp8((int)uc, false);
        float2v chi = __builtin_amdgcn_cvt_pk_f32_fp8((int)uc, true);
        float2v dlo = __builtin_amdgcn_cvt_pk_f32_fp8((int)ud, false);
        float2v dhi = __builtin_amdgcn_cvt_pk_f32_fp8((int)ud, true);
        x0 += alo[0]+blo[0]+clo[0]+dlo[0];
        x1 += alo[1]+blo[1]+clo[1]+dlo[1];
        x2 += ahi[0]+bhi[0]+chi[0]+dhi[0];
        x3 += ahi[1]+bhi[1]+chi[1]+dhi[1];
    }
    for (; e<end; e++){
        int2 c0 = cs[e];
        unsigned int ua = *(const unsigned int*)(X8 + (size_t)c0.x*PITCH8 + el);
        float2v alo = __builtin_amdgcn_cvt_pk_f32_fp8((int)ua, false);
        float2v ahi = __builtin_amdgcn_cvt_pk_f32_fp8((int)ua, true);
        x0 += alo[0]; x1 += alo[1]; x2 += ahi[0]; x3 += ahi[1];
    }
    float id = 1.f / fmaxf((float)(end-beg), 1.f);
    ushort4 o;
    o.x=f2bf(x0*id+bf2f(rv.x)); o.y=f2bf(x1*id+bf2f(rv.y));
    o.z=f2bf(x2*id+bf2f(rv.z)); o.w=f2bf(x3*id+bf2f(rv.w));
    *(ushort4*)(P + (size_t)wv*PITCH + el) = o;
}

// ---- layer GEMM via MFMA: Out = act([P|X] @ [Wn;Wl]), K=448 --------------
// Depth-2 rolling A-prefetch (round 12/13) + 212-stride LDS epilogue
// (54,272 B -> 3 blocks/CU instead of 2; write banks conflict-free).
template<int EPI>
__global__ __launch_bounds__(256) void gemm_layer_mfma_k(
        const unsigned short* __restrict__ Pb,
        const unsigned short* __restrict__ Xb,
        const unsigned short* __restrict__ Bpack,
        unsigned short* __restrict__ OutB,
        unsigned char* __restrict__ X8out,
        const float* __restrict__ gate, const float* __restrict__ ent){
    __shared__ unsigned short OutS[128*OUTS_W];
    const int tid = threadIdx.x;
    const int l   = tid & 63;
    const int w   = tid >> 6;
    const int n0  = blockIdx.x * 128;
    const int lr  = l & 15;
    const int lg  = l >> 4;
    int r0 = n0 + w*32 + lr;
    int r1 = r0 + 16;
    int c0 = r0 < N_ENT ? r0 : N_ENT-1;
    int c1 = r1 < N_ENT ? r1 : N_ENT-1;
    const unsigned short* aP0 = Pb + (size_t)c0*PITCH + lg*8;
    const unsigned short* aP1 = Pb + (size_t)c1*PITCH + lg*8;
    const unsigned short* aX0 = Xb + (size_t)c0*PITCH + lg*8;
    const unsigned short* aX1 = Xb + (size_t)c1*PITCH + lg*8;
    float4v acc[2][NF];
    #pragma unroll
    for (int f=0; f<NF; f++){
        acc[0][f] = (float4v){0.f,0.f,0.f,0.f};
        acc[1][f] = (float4v){0.f,0.f,0.f,0.f};
    }
    short8v cur0 = *(const short8v*)(aP0);
    short8v cur1 = *(const short8v*)(aP1);
    short8v nx0  = *(const short8v*)(aP0 + 32);
    short8v nx1  = *(const short8v*)(aP1 + 32);
    #pragma unroll 1
    for (int s=0; s<14; s++){
        const int t2 = (s+2 < 14) ? s+2 : 13;
        const unsigned short* b0 = (t2 < 7) ? aP0 : aX0;
        const unsigned short* b1 = (t2 < 7) ? aP1 : aX1;
        const int ks2 = (t2 < 7) ? t2 : t2-7;
        short8v nn0 = *(const short8v*)(b0 + ks2*32);
        short8v nn1 = *(const short8v*)(b1 + ks2*32);
        const unsigned short* bp = Bpack + ((size_t)(s*NF*64) + l)*8;
        #pragma unroll
        for (int f=0; f<NF; f++){
            short8v b = *(const short8v*)(bp + (size_t)f*512);
            acc[0][f] = __builtin_amdgcn_mfma_f32_16x16x32_bf16(cur0, b, acc[0][f], 0, 0, 0);
            acc[1][f] = __builtin_amdgcn_mfma_f32_16x16x32_bf16(cur1, b, acc[1][f], 0, 0, 0);
        }
        cur0 = nx0; cur1 = nx1;
        nx0 = nn0;  nx1 = nn1;
    }
    // one-pass epilogue: acc -> LDS (rrelu), then 16B stores
    #pragma unroll
    for (int f=0; f<NF; f++){
        int c = f*16 + lr;
        if (c < HDIM){
            #pragma unroll
            for (int j=0; j<4; j++){
                OutS[(w*32 + lg*4 + j)*OUTS_W + c]      = f2bf(rrelu_f(acc[0][f][j]));
                OutS[(w*32 + 16 + lg*4 + j)*OUTS_W + c] = f2bf(rrelu_f(acc[1][f][j]));
            }
        }
    }
    __syncthreads();
    for (int i = tid; i < 128*NSEG; i += 256){
        int r = i/NSEG, seg = i - r*NSEG;
        int n = n0 + r;
        if (n >= N_ENT) continue;
        short8v o;
        uint2 p8 = make_uint2(0u, 0u);
        if (seg >= 25){
            #pragma unroll
            for (int j=0;j<8;j++) o[j]=0;
        } else {
            short8v v = *(const short8v*)(&OutS[r*OUTS_W + seg*8]);
            if (EPI == 2){
                float g = gate[n];
                const float4* ef = (const float4*)(ent + (size_t)n*HDIM + seg*8);
                float4 e0 = ef[0], e1 = ef[1];
                float ev[8] = {e0.x,e0.y,e0.z,e0.w,e1.x,e1.y,e1.z,e1.w};
                #pragma unroll
                for (int j=0; j<8; j++){
                    float x = g*bf2f((unsigned short)v[j]) + (1.f-g)*ev[j];
                    o[j] = (short)f2bf(x);
                }
            } else {
                o = v;
                float f0=bf2f((unsigned short)v[0]), f1=bf2f((unsigned short)v[1]);
                float f2=bf2f((unsigned short)v[2]), f3=bf2f((unsigned short)v[3]);
                float f4=bf2f((unsigned short)v[4]), f5=bf2f((unsigned short)v[5]);
                float f6=bf2f((unsigned short)v[6]), f7=bf2f((unsigned short)v[7]);
                p8.x = pack_fp8x4(f0,f1,f2,f3);
                p8.y = pack_fp8x4(f4,f5,f6,f7);
            }
        }
        *(short8v*)(OutB + (size_t)n*PITCH + seg*8) = o;
        if (EPI == 1) *(uint2*)(X8out + (size_t)n*PITCH8 + seg*8) = p8;
    }
}

// ---- BN stats: stage 1 (32-block deterministic partial sums) ------------
__global__ __launch_bounds__(256) void bn_part_k(const unsigned short* __restrict__ hfb,
        const float* __restrict__ rel, const float* __restrict__ freq,
        const int* __restrict__ s_idx, const int* __restrict__ r_idx,
        float* __restrict__ bnpart){
    int t = threadIdx.x;
    float acc[6] = {0,0,0,0,0,0};
    for (int i = blockIdx.x*256 + t; i < BDIM*HDIM; i += BN_NB*256){
        int b = i/HDIM, h = i - b*HDIM;
        float e = bf2f(hfb[(size_t)s_idx[b]*PITCH + h]);
        float r = rel[(size_t)r_idx[b]*HDIM + h];
        float f = freq[i];
        acc[0]+=e; acc[1]+=e*e; acc[2]+=r; acc[3]+=r*r; acc[4]+=f; acc[5]+=f*f;
    }
    __shared__ float red[4][6];
    #pragma unroll
    for (int c=0;c<6;c++){
        float s = acc[c];
        #pragma unroll
        for (int off=32; off>=1; off>>=1) s += __shfl_xor(s, off);
        if ((t&63)==0) red[t>>6][c] = s;
    }
    __syncthreads();
    if (t==0){
        #pragma unroll
        for (int c=0;c<6;c++)
            bnpart[blockIdx.x*6+c] = red[0][c]+red[1][c]+red[2][c]+red[3][c];
    }
}

// ---- q row-major bf16 [512][PITCH] (bn_fin folded in), pads zeroed ------
__global__ __launch_bounds__(256) void qt_k(const unsigned short* __restrict__ hfb,
        const float* __restrict__ rel,
        const float* __restrict__ freq, const int* __restrict__ s_idx, const int* __restrict__ r_idx,
        const float* __restrict__ gamma, const float* __restrict__ beta,
        const float* __restrict__ convw, const float* __restrict__ convb,
        const float* __restrict__ bnpart, unsigned short* __restrict__ qb){
    __shared__ float bnp_s[6];
    if (threadIdx.x < 6){
        float s = 0.f;
        for (int b=0;b<BN_NB;b++) s += bnpart[b*6 + threadIdx.x];
        bnp_s[threadIdx.x] = s;
    }
    __syncthreads();
    const float inv = 1.f/(float)(BDIM*HDIM);
    float m0 = bnp_s[0]*inv, m1 = bnp_s[2]*inv, m2 = bnp_s[4]*inv;
    float i0 = rsqrtf(bnp_s[1]*inv - m0*m0 + 1e-5f);
    float i1 = rsqrtf(bnp_s[3]*inv - m1*m1 + 1e-5f);
    float i2 = rsqrtf(bnp_s[5]*inv - m2*m2 + 1e-5f);
    int i = blockIdx.x*blockDim.x + threadIdx.x;
    if (i >= BDIM*PITCH) return;
    int b = i/PITCH, h = i - b*PITCH;
    if (h >= HDIM){ qb[i] = 0; return; }
    float x0 = bf2f(hfb[(size_t)s_idx[b]*PITCH + h]);
    float x1 = rel[(size_t)r_idx[b]*HDIM + h];
    float x2 = freq[(size_t)b*HDIM + h];
    float v0 = fmaxf((x0-m0)*i0*gamma[0] + beta[0], 0.f);
    float v1 = fmaxf((x1-m1)*i1*gamma[1] + beta[1], 0.f);
    float v2 = fmaxf((x2-m2)*i2*gamma[2] + beta[2], 0.f);
    float q = v0*convw[0] + v1*convw[1] + v2*convw[2] + convb[0];
    qb[(size_t)b*PITCH + h] = f2bf(q);
}

// ---- scores[b][n] = q[b] . hf[n] via MFMA, 64-row n-tiles ---------------
__global__ __launch_bounds__(256,2) void scores_mfma_k(
        const unsigned short* __restrict__ hfb,
        const unsigned short* __restrict__ qb,
        float* __restrict__ out){
    const int tid = threadIdx.x;
    const int l   = tid & 63;
    const int w   = tid >> 6;
    const int lr  = l & 15;
    const int lg  = l >> 4;
    const int n0  = blockIdx.x * 64;
    float4v acc[8][4];
    #pragma unroll
    for (int bf=0; bf<8; bf++)
        #pragma unroll
        for (int nf=0; nf<4; nf++) acc[bf][nf] = (float4v){0,0,0,0};
    const unsigned short* hptr[4];
    #pragma unroll
    for (int nf=0; nf<4; nf++){
        int n = n0 + nf*16 + lr;
        if (n >= N_ENT) n = N_ENT-1;
        hptr[nf] = hfb + (size_t)n*PITCH + lg*8;
    }
    const unsigned short* qrow = qb + (size_t)(w*128 + lr)*PITCH + lg*8;
    for (int ks=0; ks<7; ks++){
        short8v hv[4];
        #pragma unroll
        for (int nf=0; nf<4; nf++) hv[nf] = *(const short8v*)(hptr[nf] + ks*32);
        #pragma unroll
        for (int bf=0; bf<8; bf++){
            short8v q = *(const short8v*)(qrow + (size_t)bf*16*PITCH + ks*32);
            #pragma unroll
            for (int nf=0; nf<4; nf++)
                acc[bf][nf] = __builtin_amdgcn_mfma_f32_16x16x32_bf16(q, hv[nf], acc[bf][nf], 0, 0, 0);
        }
    }
    #pragma unroll
    for (int bf=0; bf<8; bf++){
        int b = w*128 + bf*16 + lg*4;
        #pragma unroll
        for (int nf=0; nf<4; nf++){
            int n = n0 + nf*16 + lr;
            if (n >= N_ENT) continue;
            #pragma unroll
            for (int j=0; j<4; j++){
                out[(size_t)(b+j)*N_ENT + n] = acc[bf][nf][j];
            }
        }
    }
}

extern "C" void kernel_launch(void* const* d_in, const int* in_sizes, int n_in,
                              void* d_out, int out_size, void* d_ws, size_t ws_size,
                              hipStream_t stream) {
    const float* ent    = (const float*)d_in[0];
    const float* rel    = (const float*)d_in[1];
    const float* Wn1    = (const float*)d_in[2];
    const float* Wl1    = (const float*)d_in[3];
    const float* Wn2    = (const float*)d_in[4];
    const float* Wl2    = (const float*)d_in[5];
    const float* gtheta = (const float*)d_in[6];
    const float* gw     = (const float*)d_in[7];
    const float* gb     = (const float*)d_in[8];
    const float* gamma  = (const float*)d_in[9];
    const float* beta   = (const float*)d_in[10];
    const float* convw  = (const float*)d_in[11];
    const float* convb  = (const float*)d_in[12];
    const float* freq   = (const float*)d_in[13];
    const int*   src    = (const int*)d_in[14];
    const int*   dst    = (const int*)d_in[15];
    const int*   etype  = (const int*)d_in[16];
    const int*   s_idx  = (const int*)d_in[17];
    const int*   r_idx  = (const int*)d_in[18];
    float* out = (float*)d_out;

    char* ws = (char*)d_ws;
    size_t off = 0;
    auto alloc = [&](size_t bytes)->char*{
        char* p = ws + off;
        off += (bytes + 511) & ~(size_t)511;
        return p;
    };
    int*   deg      = (int*)alloc((size_t)N_ENT*4);
    int*   row_off  = (int*)alloc((size_t)(N_ENT+1)*4);
    int*   fill_pos = (int*)alloc((size_t)N_ENT*4);
    int*   partial  = (int*)alloc((size_t)SCAN_NB*4);
    int2*  cs       = (int2*)alloc((size_t)NEDGE*8);
    unsigned short* Xbuf1  = (unsigned short*)alloc((size_t)N_ENT*PITCH*2);
    unsigned short* Xbuf2  = (unsigned short*)alloc((size_t)N_ENT*PITCH*2);
    unsigned short* Pbuf   = (unsigned short*)alloc((size_t)N_ENT*PITCH*2);   // shared P1/P2
    unsigned short* relavg = (unsigned short*)alloc((size_t)N_ENT*PITCH*2);
    unsigned char*  X8_1   = (unsigned char*)alloc((size_t)N_ENT*PITCH8);
    unsigned char*  X8_2   = (unsigned char*)alloc((size_t)N_ENT*PITCH8);
    unsigned int*   rel8   = (unsigned int*)alloc((size_t)REL8_WORDS*4);
    unsigned short* Bp1    = (unsigned short*)alloc((size_t)BP_ELEMS*2);
    unsigned short* Bp2    = (unsigned short*)alloc((size_t)BP_ELEMS*2);
    unsigned short* qb     = (unsigned short*)alloc((size_t)BDIM*PITCH*2);
    float* gate   = (float*)alloc((size_t)N_ENT*4);
    float* bnpart = (float*)alloc((size_t)BN_NB*6*4);
    unsigned short* hfb = Xbuf1;   // gemm2 output reuses Xbuf1 (dead after gemm1)

    const int EB = (NEDGE + 255)/256;
    const int INIT_NB = 98 + 29 + 91 + 91 + N_ENT/4 + N_ENT/4;

    init_k<<<INIT_NB,256,0,stream>>>(ent, rel, Wn1, Wl1, Wn2, Wl2, gtheta, gw, gb,
                                     deg, rel8, Bp1, Bp2, Xbuf1, X8_1, gate);
    hist_k<<<EB,256,0,stream>>>(dst, deg);
    scan_part_k<<<SCAN_NB,256,0,stream>>>(deg, partial);
    scan_mid_k<<<1,128,0,stream>>>(partial);
    scan_fin_k<<<SCAN_NB,256,0,stream>>>(deg, partial, row_off, fill_pos);
    fill_k<<<EB,256,0,stream>>>(src, dst, etype, fill_pos, cs);

    const int NWB = N_ENT/4;             // spmm: 4 waves/block, 1 node/wave
    const int GTB = (N_ENT + 127)/128;   // gemm: 128-row tiles

    // layer 1 (emits relavg, reused by layer 2); gemm1 emits h1 bf16 + fp8
    spmm1_k<<<NWB,256,0,stream>>>(X8_1, Pbuf, (const unsigned char*)rel8, cs, row_off, relavg);
    gemm_layer_mfma_k<1><<<GTB,256,0,stream>>>(Pbuf, Xbuf1, Bp1, Xbuf2, X8_2, nullptr, nullptr);

    // layer 2 (+ gate blend) -> hfb (= Xbuf1)
    spmm2_k<<<NWB,256,0,stream>>>(X8_2, Pbuf, relavg, cs, row_off);
    gemm_layer_mfma_k<2><<<GTB,256,0,stream>>>(Pbuf, Xbuf2, Bp2, hfb, nullptr, gate, ent);

    // ConvE head
    bn_part_k<<<BN_NB,256,0,stream>>>(hfb, rel, freq, s_idx, r_idx, bnpart);
    qt_k<<<(BDIM*PITCH+255)/256,256,0,stream>>>(hfb, rel, freq, s_idx, r_idx, gamma, beta, convw, convb, bnpart, qb);

    // scores
    scores_mfma_k<<<(N_ENT+63)/64,256,0,stream>>>(hfb, qb, out);

    (void)in_sizes; (void)n_in; (void)out_size; (void)ws_size;
}

// Round 15
// 525.774 us; speedup vs baseline: 1.0042x; 1.0042x over previous
//
#include <hip/hip_runtime.h>

#define N_ENT 100000
#define HDIM  200
#define NEDGE 1000000
#define BDIM  512
#define PITCH 224            // bf16 row pitch (elems); 448B, 64B-aligned
#define PITCH8 256           // fp8 row pitch (bytes); 64B-aligned
#define NSEG  28             // PITCH/8
#define NF    13             // 13 x 16 = 208 output cols
#define OUTS_W 212           // LDS stride: 128*212*2=54272B -> 3 blocks/CU, conflict-free
#define SCAN_TILE 1024
#define SCAN_NB   ((N_ENT + SCAN_TILE - 1)/SCAN_TILE)   // 98
#define BN_NB 32
#define REL8_WORDS (460*PITCH8/4)   // 29440 4-byte words
#define BP_ELEMS   (14*NF*64*8)     // 93184

typedef short  short8v __attribute__((ext_vector_type(8)));
typedef float  float4v __attribute__((ext_vector_type(4)));
typedef float  float2v __attribute__((ext_vector_type(2)));

__device__ __forceinline__ float rrelu_f(float v){
    const float slope = (1.0f/8.0f + 1.0f/3.0f)*0.5f;
    return v >= 0.f ? v : v*slope;
}
__device__ __forceinline__ unsigned short f2bf(float f){
    unsigned int x = __float_as_uint(f);
    unsigned int r = (x + 0x7fffu + ((x >> 16) & 1u)) >> 16;
    return (unsigned short)r;
}
__device__ __forceinline__ float bf2f(unsigned short u){
    return __uint_as_float(((unsigned int)u) << 16);
}
__device__ __forceinline__ unsigned int pack_fp8x4(float a, float b, float c, float d){
    unsigned int w = 0;
    w = __builtin_amdgcn_cvt_pk_fp8_f32(a, b, w, false);
    w = __builtin_amdgcn_cvt_pk_fp8_f32(c, d, w, true);
    return w;
}

// ---- fused init: deg=0 | rel8 | Bp1 | Bp2 | Xbuf1/X8_1=ent | gate -------
__device__ __forceinline__ void pack_b(int b, const float* __restrict__ Wn,
        const float* __restrict__ Wl, unsigned short* __restrict__ Bp){
    int i = b*1024 + threadIdx.x*4;
    #pragma unroll
    for (int k=0;k<4;k++){
        int idx = i+k;
        if (idx < BP_ELEMS){
            int j = idx & 7, l = (idx >> 3) & 63, rest = idx >> 9;
            int f = rest % NF, ks = rest / NF;
            int kk = ks*32 + ((l >> 4) << 3) + j;
            int c  = f*16 + (l & 15);
            float v = 0.f;
            if (c < HDIM){
                if (kk < 200)                   v = Wn[(size_t)kk*HDIM + c];
                else if (kk >= 224 && kk < 424) v = Wl[(size_t)(kk-224)*HDIM + c];
            }
            Bp[idx] = f2bf(v);
        }
    }
}

__global__ __launch_bounds__(256) void init_k(const float* __restrict__ ent,
        const float* __restrict__ rel,
        const float* __restrict__ Wn1, const float* __restrict__ Wl1,
        const float* __restrict__ Wn2, const float* __restrict__ Wl2,
        const float* __restrict__ gtheta, const float* __restrict__ gw,
        const float* __restrict__ gb,
        int* __restrict__ deg, unsigned int* __restrict__ rel8,
        unsigned short* __restrict__ Bp1, unsigned short* __restrict__ Bp2,
        unsigned short* __restrict__ Xbuf1, unsigned char* __restrict__ X8_1,
        float* __restrict__ gate){
    int b = blockIdx.x;
    if (b < 98){
        int i = b*1024 + threadIdx.x*4;
        if (i+3 < N_ENT) *(int4*)(deg+i) = make_int4(0,0,0,0);
        else { for (int k=0;k<4;k++) if (i+k < N_ENT) deg[i+k]=0; }
        return;
    }
    b -= 98;
    if (b < 29){
        int i = b*1024 + threadIdx.x*4;
        #pragma unroll
        for (int k=0;k<4;k++){
            int idx = i+k;
            if (idx < REL8_WORDS){
                int r = idx >> 6;              // 64 words per 256B row
                int c = (idx & 63) * 4;        // elem offset
                float v0=0.f,v1=0.f,v2=0.f,v3=0.f;
                if (c < HDIM){
                    const float* rp = rel + (size_t)r*HDIM + c;
                    v0 = rp[0];
                    if (c+1 < HDIM) v1 = rp[1];
                    if (c+2 < HDIM) v2 = rp[2];
                    if (c+3 < HDIM) v3 = rp[3];
                }
                rel8[idx] = pack_fp8x4(v0,v1,v2,v3);
            }
        }
        return;
    }
    b -= 29;
    if (b < 91){ pack_b(b, Wn1, Wl1, Bp1); return; }
    b -= 91;
    if (b < 91){ pack_b(b, Wn2, Wl2, Bp2); return; }
    b -= 91;
    int w = threadIdx.x >> 6, l = threadIdx.x & 63;
    if (b < N_ENT/4){
        // Xbuf1 (bf16) + X8_1 (fp8), 4 rows/block
        if (l >= 56) return;
        int n = b*4 + w;
        int el = 4*l;
        ushort4 o;
        float4 v = make_float4(0.f,0.f,0.f,0.f);
        if (el < HDIM) v = *(const float4*)(ent + (size_t)n*HDIM + el);
        o.x=f2bf(v.x); o.y=f2bf(v.y); o.z=f2bf(v.z); o.w=f2bf(v.w);
        *(ushort4*)(Xbuf1 + (size_t)n*PITCH + el) = o;
        *(unsigned int*)(X8_1 + (size_t)n*PITCH8 + el) = pack_fp8x4(v.x,v.y,v.z,v.w);
        return;
    }
    b -= N_ENT/4;
    {   // gate: 4 nodes/block, one wave each
        int n = b*4 + w;
        const float* t = gtheta + (size_t)n*HDIM;
        float s = t[l]*gw[l] + t[64+l]*gw[64+l] + t[128+l]*gw[128+l];
        if (l<8) s += t[192+l]*gw[192+l];
        #pragma unroll
        for (int off=32; off>=1; off>>=1) s += __shfl_xor(s, off);
        if (l==0) gate[n] = 1.f/(1.f + expf(-(s + gb[0])));
    }
}

// ---- CSR build ----------------------------------------------------------
__global__ void hist_k(const int* __restrict__ dst, int* __restrict__ deg){
    int e = blockIdx.x*blockDim.x + threadIdx.x;
    if (e < NEDGE) atomicAdd(&deg[dst[e]], 1);
}

__global__ __launch_bounds__(256) void scan_part_k(const int* __restrict__ deg, int* __restrict__ partial){
    int t = threadIdx.x;
    int base = blockIdx.x*SCAN_TILE + t*4;
    int s = 0;
    if (base + 3 < N_ENT){
        int4 v = *(const int4*)(deg + base);
        s = v.x + v.y + v.z + v.w;
    } else {
        for (int i=0;i<4;i++) if (base+i < N_ENT) s += deg[base+i];
    }
    #pragma unroll
    for (int off=32; off>=1; off>>=1) s += __shfl_xor(s, off);
    __shared__ int ws[4];
    if ((t&63)==0) ws[t>>6] = s;
    __syncthreads();
    if (t==0) partial[blockIdx.x] = ws[0]+ws[1]+ws[2]+ws[3];
}

__global__ void scan_mid_k(int* __restrict__ partial){
    __shared__ int sh[128];
    int t = threadIdx.x;
    int v = (t < SCAN_NB) ? partial[t] : 0;
    sh[t] = v;
    __syncthreads();
    for (int off=1; off<128; off<<=1){
        int u = (t>=off) ? sh[t-off] : 0;
        __syncthreads();
        sh[t] += u;
        __syncthreads();
    }
    if (t < SCAN_NB) partial[t] = sh[t] - v;   // exclusive
}

__global__ __launch_bounds__(256) void scan_fin_k(const int* __restrict__ deg, const int* __restrict__ partial,
        int* __restrict__ row_off, int* __restrict__ fill_pos){
    int t = threadIdx.x;
    int lane = t & 63;
    int base = blockIdx.x*SCAN_TILE + t*4;
    int v0=0,v1=0,v2=0,v3=0;
    if (base+3 < N_ENT){
        int4 v = *(const int4*)(deg + base);
        v0=v.x; v1=v.y; v2=v.z; v3=v.w;
    } else {
        if (base   < N_ENT) v0 = deg[base];
        if (base+1 < N_ENT) v1 = deg[base+1];
        if (base+2 < N_ENT) v2 = deg[base+2];
        if (base+3 < N_ENT) v3 = deg[base+3];
    }
    int s = v0+v1+v2+v3;
    int inc = s;
    #pragma unroll
    for (int off=1; off<64; off<<=1){
        int u = __shfl_up(inc, off);
        if (lane >= off) inc += u;
    }
    __shared__ int wsum[4];
    if (lane==63) wsum[t>>6] = inc;
    __syncthreads();
    int w = t>>6;
    int woff = 0;
    for (int i=0;i<w;i++) woff += wsum[i];
    int exc = partial[blockIdx.x] + woff + inc - s;
    int r0 = exc, r1 = exc+v0, r2 = exc+v0+v1, r3 = exc+v0+v1+v2;
    if (base+3 < N_ENT){
        *(int4*)(row_off+base)  = make_int4(r0,r1,r2,r3);
        *(int4*)(fill_pos+base) = make_int4(r0,r1,r2,r3);
    } else {
        if (base   < N_ENT){ row_off[base]  =r0; fill_pos[base]  =r0; }
        if (base+1 < N_ENT){ row_off[base+1]=r1; fill_pos[base+1]=r1; }
        if (base+2 < N_ENT){ row_off[base+2]=r2; fill_pos[base+2]=r2; }
        if (base+3 < N_ENT){ row_off[base+3]=r3; fill_pos[base+3]=r3; }
    }
    if (blockIdx.x==0 && t==0) row_off[N_ENT] = NEDGE;
}

__global__ void fill_k(const int* __restrict__ src, const int* __restrict__ dst, const int* __restrict__ et,
                       int* __restrict__ fill_pos, int2* __restrict__ cs){
    int e = blockIdx.x*blockDim.x + threadIdx.x;
    if (e < NEDGE){
        int p = atomicAdd(&fill_pos[dst[e]], 1);
        cs[p] = make_int2(src[e], et[e]);
    }
}

// ---- spmm layer 1: fp8 X-gather + fp8 rel-gather, write P1 and relavg ---
__global__ __launch_bounds__(256) void spmm1_k(const unsigned char* __restrict__ X8,
        unsigned short* __restrict__ P,
        const unsigned char* __restrict__ rel8,
        const int2* __restrict__ cs,
        const int* __restrict__ row_off,
        unsigned short* __restrict__ relavg){
    int wv = (blockIdx.x*256 + threadIdx.x) >> 6;
    int l = threadIdx.x & 63;
    if (l >= 56) return;
    int beg = row_off[wv], end = row_off[wv+1];
    const int el = 4*l;
    float x0=0.f,x1=0.f,x2=0.f,x3=0.f;
    float r0=0.f,r1=0.f,r2=0.f,r3=0.f;
    int e = beg;
    for (; e+4 <= end; e+=4){
        int2 c0 = cs[e], c1 = cs[e+1], c2 = cs[e+2], c3 = cs[e+3];
        unsigned int ua = *(const unsigned int*)(X8 + (size_t)c0.x*PITCH8 + el);
        unsigned int ub = *(const unsigned int*)(X8 + (size_t)c1.x*PITCH8 + el);
        unsigned int uc = *(const unsigned int*)(X8 + (size_t)c2.x*PITCH8 + el);
        unsigned int ud = *(const unsigned int*)(X8 + (size_t)c3.x*PITCH8 + el);
        unsigned int va = *(const unsigned int*)(rel8 + (size_t)c0.y*PITCH8 + el);
        unsigned int vb = *(const unsigned int*)(rel8 + (size_t)c1.y*PITCH8 + el);
        unsigned int vc = *(const unsigned int*)(rel8 + (size_t)c2.y*PITCH8 + el);
        unsigned int vd = *(const unsigned int*)(rel8 + (size_t)c3.y*PITCH8 + el);
        float2v alo = __builtin_amdgcn_cvt_pk_f32_fp8((int)ua, false);
        float2v ahi = __builtin_amdgcn_cvt_pk_f32_fp8((int)ua, true);
        float2v blo = __builtin_amdgcn_cvt_pk_f32_fp8((int)ub, false);
        float2v bhi = __builtin_amdgcn_cvt_pk_f32_fp8((int)ub, true);
        float2v clo = __builtin_amdgcn_cvt_pk_f32_fp8((int)uc, false);
        float2v chi = __builtin_amdgcn_cvt_pk_f32_fp8((int)uc, true);
        float2v dlo = __builtin_amdgcn_cvt_pk_f32_fp8((int)ud, false);
        float2v dhi = __builtin_amdgcn_cvt_pk_f32_fp8((int)ud, true);
        float2v ralo = __builtin_amdgcn_cvt_pk_f32_fp8((int)va, false);
        float2v rahi = __builtin_amdgcn_cvt_pk_f32_fp8((int)va, true);
        float2v rblo = __builtin_amdgcn_cvt_pk_f32_fp8((int)vb, false);
        float2v rbhi = __builtin_amdgcn_cvt_pk_f32_fp8((int)vb, true);
        float2v rclo = __builtin_amdgcn_cvt_pk_f32_fp8((int)vc, false);
        float2v rchi = __builtin_amdgcn_cvt_pk_f32_fp8((int)vc, true);
        float2v rdlo = __builtin_amdgcn_cvt_pk_f32_fp8((int)vd, false);
        float2v rdhi = __builtin_amdgcn_cvt_pk_f32_fp8((int)vd, true);
        x0 += alo[0]+blo[0]+clo[0]+dlo[0];
        x1 += alo[1]+blo[1]+clo[1]+dlo[1];
        x2 += ahi[0]+bhi[0]+chi[0]+dhi[0];
        x3 += ahi[1]+bhi[1]+chi[1]+dhi[1];
        r0 += ralo[0]+rblo[0]+rclo[0]+rdlo[0];
        r1 += ralo[1]+rblo[1]+rclo[1]+rdlo[1];
        r2 += rahi[0]+rbhi[0]+rchi[0]+rdhi[0];
        r3 += rahi[1]+rbhi[1]+rchi[1]+rdhi[1];
    }
    for (; e<end; e++){
        int2 c0 = cs[e];
        unsigned int ua = *(const unsigned int*)(X8 + (size_t)c0.x*PITCH8 + el);
        unsigned int va = *(const unsigned int*)(rel8 + (size_t)c0.y*PITCH8 + el);
        float2v alo = __builtin_amdgcn_cvt_pk_f32_fp8((int)ua, false);
        float2v ahi = __builtin_amdgcn_cvt_pk_f32_fp8((int)ua, true);
        float2v ralo = __builtin_amdgcn_cvt_pk_f32_fp8((int)va, false);
        float2v rahi = __builtin_amdgcn_cvt_pk_f32_fp8((int)va, true);
        x0 += alo[0]; x1 += alo[1]; x2 += ahi[0]; x3 += ahi[1];
        r0 += ralo[0]; r1 += ralo[1]; r2 += rahi[0]; r3 += rahi[1];
    }
    float id = 1.f / fmaxf((float)(end-beg), 1.f);
    float g0 = r0*id, g1 = r1*id, g2 = r2*id, g3 = r3*id;
    ushort4 rv; rv.x=f2bf(g0); rv.y=f2bf(g1); rv.z=f2bf(g2); rv.w=f2bf(g3);
    *(ushort4*)(relavg + (size_t)wv*PITCH + el) = rv;
    ushort4 o;
    o.x=f2bf(x0*id+g0); o.y=f2bf(x1*id+g1); o.z=f2bf(x2*id+g2); o.w=f2bf(x3*id+g3);
    *(ushort4*)(P + (size_t)wv*PITCH + el) = o;
}

// ---- spmm layer 2: fp8 X-gather (8-wide) + stream relavg, write P2 ------
__global__ __launch_bounds__(256) void spmm2_k(const unsigned char* __restrict__ X8,
        unsigned short* __restrict__ P,
        const unsigned short* __restrict__ relavg,
        const int2* __restrict__ cs,
        const int* __restrict__ row_off){
    int wv = (blockIdx.x*256 + threadIdx.x) >> 6;
    int l = threadIdx.x & 63;
    if (l >= 56) return;
    int beg = row_off[wv], end = row_off[wv+1];
    const int el = 4*l;
    ushort4 rv = *(const ushort4*)(relavg + (size_t)wv*PITCH + el);
    float x0=0.f,x1=0.f,x2=0.f,x3=0.f;
    int e = beg;
    for (; e+8 <= end; e+=8){
        int2 c0 = cs[e],   c1 = cs[e+1], c2 = cs[e+2], c3 = cs[e+3];
        int2 c4 = cs[e+4], c5 = cs[e+5], c6 = cs[e+6], c7 = cs[e+7];
        unsigned int u0 = *(const unsigned int*)(X8 + (size_t)c0.x*PITCH8 + el);
        unsigned int u1 = *(const unsigned int*)(X8 + (size_t)c1.x*PITCH8 + el);
        unsigned int u2 = *(const unsigned int*)(X8 + (size_t)c2.x*PITCH8 + el);
        unsigned int u3 = *(const unsigned int*)(X8 + (size_t)c3.x*PITCH8 + el);
        unsigned int u4 = *(const unsigned int*)(X8 + (size_t)c4.x*PITCH8 + el);
        unsigned int u5 = *(const unsigned int*)(X8 + (size_t)c5.x*PITCH8 + el);
        unsigned int u6 = *(const unsigned int*)(X8 + (size_t)c6.x*PITCH8 + el);
        unsigned int u7 = *(const unsigned int*)(X8 + (size_t)c7.x*PITCH8 + el);
        float2v l0 = __builtin_amdgcn_cvt_pk_f32_fp8((int)u0, false);
        float2v h0 = __builtin_amdgcn_cvt_pk_f32_fp8((int)u0, true);
        float2v l1 = __builtin_amdgcn_cvt_pk_f32_fp8((int)u1, false);
        float2v h1 = __builtin_amdgcn_cvt_pk_f32_fp8((int)u1, true);
        float2v l2 = __builtin_amdgcn_cvt_pk_f32_fp8((int)u2, false);
        float2v h2 = __builtin_amdgcn_cvt_pk_f32_fp8((int)u2, true);
        float2v l3 = __builtin_amdgcn_cvt_pk_f32_fp8((int)u3, false);
        float2v h3 = __builtin_amdgcn_cvt_pk_f32_fp8((int)u3, true);
        float2v l4 = __builtin_amdgcn_cvt_pk_f32_fp8((int)u4, false);
        float2v h4 = __builtin_amdgcn_cvt_pk_f32_fp8((int)u4, true);
        float2v l5 = __builtin_amdgcn_cvt_pk_f32_fp8((int)u5, false);
        float2v h5 = __builtin_amdgcn_cvt_pk_f32_fp8((int)u5, true);
        float2v l6 = __builtin_amdgcn_cvt_pk_f32_fp8((int)u6, false);
        float2v h6 = __builtin_amdgcn_cvt_pk_f32_fp8((int)u6, true);
        float2v l7 = __builtin_amdgcn_cvt_pk_f32_fp8((int)u7, false);
        float2v h7 = __builtin_amdgcn_cvt_pk_f32_fp8((int)u7, true);
        x0 += l0[0]+l1[0]+l2[0]+l3[0]+l4[0]+l5[0]+l6[0]+l7[0];
        x1 += l0[1]+l1[1]+l2[1]+l3[1]+l4[1]+l5[1]+l6[1]+l7[1];
        x2 += h0[0]+h1[0]+h2[0]+h3[0]+h4[0]+h5[0]+h6[0]+h7[0];
        x3 += h0[1]+h1[1]+h2[1]+h3[1]+h4[1]+h5[1]+h6[1]+h7[1];
    }
    for (; e+4 <= end; e+=4){
        int2 c0 = cs[e], c1 = cs[e+1], c2 = cs[e+2], c3 = cs[e+3];
        unsigned int u0 = *(const unsigned int*)(X8 + (size_t)c0.x*PITCH8 + el);
        unsigned int u1 = *(const unsigned int*)(X8 + (size_t)c1.x*PITCH8 + el);
        unsigned int u2 = *(const unsigned int*)(X8 + (size_t)c2.x*PITCH8 + el);
        unsigned int u3 = *(const unsigned int*)(X8 + (size_t)c3.x*PITCH8 + el);
        float2v l0 = __builtin_amdgcn_cvt_pk_f32_fp8((int)u0, false);
        float2v h0 = __builtin_amdgcn_cvt_pk_f32_fp8((int)u0, true);
        float2v l1 = __builtin_amdgcn_cvt_pk_f32_fp8((int)u1, false);
        float2v h1 = __builtin_amdgcn_cvt_pk_f32_fp8((int)u1, true);
        float2v l2 = __builtin_amdgcn_cvt_pk_f32_fp8((int)u2, false);
        float2v h2 = __builtin_amdgcn_cvt_pk_f32_fp8((int)u2, true);
        float2v l3 = __builtin_amdgcn_cvt_pk_f32_fp8((int)u3, false);
        float2v h3 = __builtin_amdgcn_cvt_pk_f32_fp8((int)u3, true);
        x0 += l0[0]+l1[0]+l2[0]+l3[0];
        x1 += l0[1]+l1[1]+l2[1]+l3[1];
        x2 += h0[0]+h1[0]+h2[0]+h3[0];
        x3 += h0[1]+h1[1]+h2[1]+h3[1];
    }
    for (; e<end; e++){
        int2 c0 = cs[e];
        unsigned int u0 = *(const unsigned int*)(X8 + (size_t)c0.x*PITCH8 + el);
        float2v l0 = __builtin_amdgcn_cvt_pk_f32_fp8((int)u0, false);
        float2v h0 = __builtin_amdgcn_cvt_pk_f32_fp8((int)u0, true);
        x0 += l0[0]; x1 += l0[1]; x2 += h0[0]; x3 += h0[1];
    }
    float id = 1.f / fmaxf((float)(end-beg), 1.f);
    ushort4 o;
    o.x=f2bf(x0*id+bf2f(rv.x)); o.y=f2bf(x1*id+bf2f(rv.y));
    o.z=f2bf(x2*id+bf2f(rv.z)); o.w=f2bf(x3*id+bf2f(rv.w));
    *(ushort4*)(P + (size_t)wv*PITCH + el) = o;
}

// ---- layer GEMM via MFMA: Out = act([P|X] @ [Wn;Wl]), K=448 --------------
// Depth-3 rolling A-prefetch (named register pairs, rolled loop) +
// 212-stride LDS epilogue (3 blocks/CU).
template<int EPI>
__global__ __launch_bounds__(256) void gemm_layer_mfma_k(
        const unsigned short* __restrict__ Pb,
        const unsigned short* __restrict__ Xb,
        const unsigned short* __restrict__ Bpack,
        unsigned short* __restrict__ OutB,
        unsigned char* __restrict__ X8out,
        const float* __restrict__ gate, const float* __restrict__ ent){
    __shared__ unsigned short OutS[128*OUTS_W];
    const int tid = threadIdx.x;
    const int l   = tid & 63;
    const int w   = tid >> 6;
    const int n0  = blockIdx.x * 128;
    const int lr  = l & 15;
    const int lg  = l >> 4;
    int r0 = n0 + w*32 + lr;
    int r1 = r0 + 16;
    int c0 = r0 < N_ENT ? r0 : N_ENT-1;
    int c1 = r1 < N_ENT ? r1 : N_ENT-1;
    const unsigned short* aP0 = Pb + (size_t)c0*PITCH + lg*8;
    const unsigned short* aP1 = Pb + (size_t)c1*PITCH + lg*8;
    const unsigned short* aX0 = Xb + (size_t)c0*PITCH + lg*8;
    const unsigned short* aX1 = Xb + (size_t)c1*PITCH + lg*8;
    float4v acc[2][NF];
    #pragma unroll
    for (int f=0; f<NF; f++){
        acc[0][f] = (float4v){0.f,0.f,0.f,0.f};
        acc[1][f] = (float4v){0.f,0.f,0.f,0.f};
    }
    short8v cur0 = *(const short8v*)(aP0);
    short8v cur1 = *(const short8v*)(aP1);
    short8v pf1_0 = *(const short8v*)(aP0 + 32);
    short8v pf1_1 = *(const short8v*)(aP1 + 32);
    short8v pf2_0 = *(const short8v*)(aP0 + 64);
    short8v pf2_1 = *(const short8v*)(aP1 + 64);
    #pragma unroll 1
    for (int s=0; s<14; s++){
        const int t3 = (s+3 < 14) ? s+3 : 13;
        const unsigned short* b0 = (t3 < 7) ? aP0 : aX0;
        const unsigned short* b1 = (t3 < 7) ? aP1 : aX1;
        const int ks3 = (t3 < 7) ? t3 : t3-7;
        short8v nn0 = *(const short8v*)(b0 + ks3*32);
        short8v nn1 = *(const short8v*)(b1 + ks3*32);
        const unsigned short* bp = Bpack + ((size_t)(s*NF*64) + l)*8;
        #pragma unroll
        for (int f=0; f<NF; f++){
            short8v b = *(const short8v*)(bp + (size_t)f*512);
            acc[0][f] = __builtin_amdgcn_mfma_f32_16x16x32_bf16(cur0, b, acc[0][f], 0, 0, 0);
            acc[1][f] = __builtin_amdgcn_mfma_f32_16x16x32_bf16(cur1, b, acc[1][f], 0, 0, 0);
        }
        cur0 = pf1_0; cur1 = pf1_1;
        pf1_0 = pf2_0; pf1_1 = pf2_1;
        pf2_0 = nn0;  pf2_1 = nn1;
    }
    // one-pass epilogue: acc -> LDS (rrelu), then 16B stores
    #pragma unroll
    for (int f=0; f<NF; f++){
        int c = f*16 + lr;
        if (c < HDIM){
            #pragma unroll
            for (int j=0; j<4; j++){
                OutS[(w*32 + lg*4 + j)*OUTS_W + c]      = f2bf(rrelu_f(acc[0][f][j]));
                OutS[(w*32 + 16 + lg*4 + j)*OUTS_W + c] = f2bf(rrelu_f(acc[1][f][j]));
            }
        }
    }
    __syncthreads();
    for (int i = tid; i < 128*NSEG; i += 256){
        int r = i/NSEG, seg = i - r*NSEG;
        int n = n0 + r;
        if (n >= N_ENT) continue;
        short8v o;
        uint2 p8 = make_uint2(0u, 0u);
        if (seg >= 25){
            #pragma unroll
            for (int j=0;j<8;j++) o[j]=0;
        } else {
            short8v v = *(const short8v*)(&OutS[r*OUTS_W + seg*8]);
            if (EPI == 2){
                float g = gate[n];
                const float4* ef = (const float4*)(ent + (size_t)n*HDIM + seg*8);
                float4 e0 = ef[0], e1 = ef[1];
                float ev[8] = {e0.x,e0.y,e0.z,e0.w,e1.x,e1.y,e1.z,e1.w};
                #pragma unroll
                for (int j=0; j<8; j++){
                    float x = g*bf2f((unsigned short)v[j]) + (1.f-g)*ev[j];
                    o[j] = (short)f2bf(x);
                }
            } else {
                o = v;
                float f0=bf2f((unsigned short)v[0]), f1=bf2f((unsigned short)v[1]);
                float f2=bf2f((unsigned short)v[2]), f3=bf2f((unsigned short)v[3]);
                float f4=bf2f((unsigned short)v[4]), f5=bf2f((unsigned short)v[5]);
                float f6=bf2f((unsigned short)v[6]), f7=bf2f((unsigned short)v[7]);
                p8.x = pack_fp8x4(f0,f1,f2,f3);
                p8.y = pack_fp8x4(f4,f5,f6,f7);
            }
        }
        *(short8v*)(OutB + (size_t)n*PITCH + seg*8) = o;
        if (EPI == 1) *(uint2*)(X8out + (size_t)n*PITCH8 + seg*8) = p8;
    }
}

// ---- BN stats: stage 1 (32-block deterministic partial sums) ------------
__global__ __launch_bounds__(256) void bn_part_k(const unsigned short* __restrict__ hfb,
        const float* __restrict__ rel, const float* __restrict__ freq,
        const int* __restrict__ s_idx, const int* __restrict__ r_idx,
        float* __restrict__ bnpart){
    int t = threadIdx.x;
    float acc[6] = {0,0,0,0,0,0};
    for (int i = blockIdx.x*256 + t; i < BDIM*HDIM; i += BN_NB*256){
        int b = i/HDIM, h = i - b*HDIM;
        float e = bf2f(hfb[(size_t)s_idx[b]*PITCH + h]);
        float r = rel[(size_t)r_idx[b]*HDIM + h];
        float f = freq[i];
        acc[0]+=e; acc[1]+=e*e; acc[2]+=r; acc[3]+=r*r; acc[4]+=f; acc[5]+=f*f;
    }
    __shared__ float red[4][6];
    #pragma unroll
    for (int c=0;c<6;c++){
        float s = acc[c];
        #pragma unroll
        for (int off=32; off>=1; off>>=1) s += __shfl_xor(s, off);
        if ((t&63)==0) red[t>>6][c] = s;
    }
    __syncthreads();
    if (t==0){
        #pragma unroll
        for (int c=0;c<6;c++)
            bnpart[blockIdx.x*6+c] = red[0][c]+red[1][c]+red[2][c]+red[3][c];
    }
}

// ---- q row-major bf16 [512][PITCH] (bn_fin folded in), pads zeroed ------
__global__ __launch_bounds__(256) void qt_k(const unsigned short* __restrict__ hfb,
        const float* __restrict__ rel,
        const float* __restrict__ freq, const int* __restrict__ s_idx, const int* __restrict__ r_idx,
        const float* __restrict__ gamma, const float* __restrict__ beta,
        const float* __restrict__ convw, const float* __restrict__ convb,
        const float* __restrict__ bnpart, unsigned short* __restrict__ qb){
    __shared__ float bnp_s[6];
    if (threadIdx.x < 6){
        float s = 0.f;
        for (int b=0;b<BN_NB;b++) s += bnpart[b*6 + threadIdx.x];
        bnp_s[threadIdx.x] = s;
    }
    __syncthreads();
    const float inv = 1.f/(float)(BDIM*HDIM);
    float m0 = bnp_s[0]*inv, m1 = bnp_s[2]*inv, m2 = bnp_s[4]*inv;
    float i0 = rsqrtf(bnp_s[1]*inv - m0*m0 + 1e-5f);
    float i1 = rsqrtf(bnp_s[3]*inv - m1*m1 + 1e-5f);
    float i2 = rsqrtf(bnp_s[5]*inv - m2*m2 + 1e-5f);
    int i = blockIdx.x*blockDim.x + threadIdx.x;
    if (i >= BDIM*PITCH) return;
    int b = i/PITCH, h = i - b*PITCH;
    if (h >= HDIM){ qb[i] = 0; return; }
    float x0 = bf2f(hfb[(size_t)s_idx[b]*PITCH + h]);
    float x1 = rel[(size_t)r_idx[b]*HDIM + h];
    float x2 = freq[(size_t)b*HDIM + h];
    float v0 = fmaxf((x0-m0)*i0*gamma[0] + beta[0], 0.f);
    float v1 = fmaxf((x1-m1)*i1*gamma[1] + beta[1], 0.f);
    float v2 = fmaxf((x2-m2)*i2*gamma[2] + beta[2], 0.f);
    float q = v0*convw[0] + v1*convw[1] + v2*convw[2] + convb[0];
    qb[(size_t)b*PITCH + h] = f2bf(q);
}

// ---- scores[b][n] = q[b] . hf[n] via MFMA, 64-row n-tiles ---------------
__global__ __launch_bounds__(256,2) void scores_mfma_k(
        const unsigned short* __restrict__ hfb,
        const unsigned short* __restrict__ qb,
        float* __restrict__ out){
    const int tid = threadIdx.x;
    const int l   = tid & 63;
    const int w   = tid >> 6;
    const int lr  = l & 15;
    const int lg  = l >> 4;
    const int n0  = blockIdx.x * 64;
    float4v acc[8][4];
    #pragma unroll
    for (int bf=0; bf<8; bf++)
        #pragma unroll
        for (int nf=0; nf<4; nf++) acc[bf][nf] = (float4v){0,0,0,0};
    const unsigned short* hptr[4];
    #pragma unroll
    for (int nf=0; nf<4; nf++){
        int n = n0 + nf*16 + lr;
        if (n >= N_ENT) n = N_ENT-1;
        hptr[nf] = hfb + (size_t)n*PITCH + lg*8;
    }
    const unsigned short* qrow = qb + (size_t)(w*128 + lr)*PITCH + lg*8;
    for (int ks=0; ks<7; ks++){
        short8v hv[4];
        #pragma unroll
        for (int nf=0; nf<4; nf++) hv[nf] = *(const short8v*)(hptr[nf] + ks*32);
        #pragma unroll
        for (int bf=0; bf<8; bf++){
            short8v q = *(const short8v*)(qrow + (size_t)bf*16*PITCH + ks*32);
            #pragma unroll
            for (int nf=0; nf<4; nf++)
                acc[bf][nf] = __builtin_amdgcn_mfma_f32_16x16x32_bf16(q, hv[nf], acc[bf][nf], 0, 0, 0);
        }
    }
    #pragma unroll
    for (int bf=0; bf<8; bf++){
        int b = w*128 + bf*16 + lg*4;
        #pragma unroll
        for (int nf=0; nf<4; nf++){
            int n = n0 + nf*16 + lr;
            if (n >= N_ENT) continue;
            #pragma unroll
            for (int j=0; j<4; j++){
                out[(size_t)(b+j)*N_ENT + n] = acc[bf][nf][j];
            }
        }
    }
}

extern "C" void kernel_launch(void* const* d_in, const int* in_sizes, int n_in,
                              void* d_out, int out_size, void* d_ws, size_t ws_size,
                              hipStream_t stream) {
    const float* ent    = (const float*)d_in[0];
    const float* rel    = (const float*)d_in[1];
    const float* Wn1    = (const float*)d_in[2];
    const float* Wl1    = (const float*)d_in[3];
    const float* Wn2    = (const float*)d_in[4];
    const float* Wl2    = (const float*)d_in[5];
    const float* gtheta = (const float*)d_in[6];
    const float* gw     = (const float*)d_in[7];
    const float* gb     = (const float*)d_in[8];
    const float* gamma  = (const float*)d_in[9];
    const float* beta   = (const float*)d_in[10];
    const float* convw  = (const float*)d_in[11];
    const float* convb  = (const float*)d_in[12];
    const float* freq   = (const float*)d_in[13];
    const int*   src    = (const int*)d_in[14];
    const int*   dst    = (const int*)d_in[15];
    const int*   etype  = (const int*)d_in[16];
    const int*   s_idx  = (const int*)d_in[17];
    const int*   r_idx  = (const int*)d_in[18];
    float* out = (float*)d_out;

    char* ws = (char*)d_ws;
    size_t off = 0;
    auto alloc = [&](size_t bytes)->char*{
        char* p = ws + off;
        off += (bytes + 511) & ~(size_t)511;
        return p;
    };
    int*   deg      = (int*)alloc((size_t)N_ENT*4);
    int*   row_off  = (int*)alloc((size_t)(N_ENT+1)*4);
    int*   fill_pos = (int*)alloc((size_t)N_ENT*4);
    int*   partial  = (int*)alloc((size_t)SCAN_NB*4);
    int2*  cs       = (int2*)alloc((size_t)NEDGE*8);
    unsigned short* Xbuf1  = (unsigned short*)alloc((size_t)N_ENT*PITCH*2);
    unsigned short* Xbuf2  = (unsigned short*)alloc((size_t)N_ENT*PITCH*2);
    unsigned short* Pbuf   = (unsigned short*)alloc((size_t)N_ENT*PITCH*2);   // shared P1/P2
    unsigned short* relavg = (unsigned short*)alloc((size_t)N_ENT*PITCH*2);
    unsigned char*  X8_1   = (unsigned char*)alloc((size_t)N_ENT*PITCH8);
    unsigned char*  X8_2   = (unsigned char*)alloc((size_t)N_ENT*PITCH8);
    unsigned int*   rel8   = (unsigned int*)alloc((size_t)REL8_WORDS*4);
    unsigned short* Bp1    = (unsigned short*)alloc((size_t)BP_ELEMS*2);
    unsigned short* Bp2    = (unsigned short*)alloc((size_t)BP_ELEMS*2);
    unsigned short* qb     = (unsigned short*)alloc((size_t)BDIM*PITCH*2);
    float* gate   = (float*)alloc((size_t)N_ENT*4);
    float* bnpart = (float*)alloc((size_t)BN_NB*6*4);
    unsigned short* hfb = Xbuf1;   // gemm2 output reuses Xbuf1 (dead after gemm1)

    const int EB = (NEDGE + 255)/256;
    const int INIT_NB = 98 + 29 + 91 + 91 + N_ENT/4 + N_ENT/4;

    init_k<<<INIT_NB,256,0,stream>>>(ent, rel, Wn1, Wl1, Wn2, Wl2, gtheta, gw, gb,
                                     deg, rel8, Bp1, Bp2, Xbuf1, X8_1, gate);
    hist_k<<<EB,256,0,stream>>>(dst, deg);
    scan_part_k<<<SCAN_NB,256,0,stream>>>(deg, partial);
    scan_mid_k<<<1,128,0,stream>>>(partial);
    scan_fin_k<<<SCAN_NB,256,0,stream>>>(deg, partial, row_off, fill_pos);
    fill_k<<<EB,256,0,stream>>>(src, dst, etype, fill_pos, cs);

    const int NWB = N_ENT/4;             // spmm: 4 waves/block, 1 node/wave
    const int GTB = (N_ENT + 127)/128;   // gemm: 128-row tiles

    // layer 1 (emits relavg, reused by layer 2); gemm1 emits h1 bf16 + fp8
    spmm1_k<<<NWB,256,0,stream>>>(X8_1, Pbuf, (const unsigned char*)rel8, cs, row_off, relavg);
    gemm_layer_mfma_k<1><<<GTB,256,0,stream>>>(Pbuf, Xbuf1, Bp1, Xbuf2, X8_2, nullptr, nullptr);

    // layer 2 (+ gate blend) -> hfb (= Xbuf1)
    spmm2_k<<<NWB,256,0,stream>>>(X8_2, Pbuf, relavg, cs, row_off);
    gemm_layer_mfma_k<2><<<GTB,256,0,stream>>>(Pbuf, Xbuf2, Bp2, hfb, nullptr, gate, ent);

    // ConvE head
    bn_part_k<<<BN_NB,256,0,stream>>>(hfb, rel, freq, s_idx, r_idx, bnpart);
    qt_k<<<(BDIM*PITCH+255)/256,256,0,stream>>>(hfb, rel, freq, s_idx, r_idx, gamma, beta, convw, convb, bnpart, qb);

    // scores
    scores_mfma_k<<<(N_ENT+63)/64,256,0,stream>>>(hfb, qb, out);

    (void)in_sizes; (void)n_in; (void)out_size; (void)ws_size;
}